// Round 1
// baseline (333.582 us; speedup 1.0000x reference)
//
#include <hip/hip_runtime.h>

// Fused SE(3) joint-update kernel.
// Per pose n (row-major 4x4 T, bottom row is exactly [0,0,0,1] by construction):
//   revTwist  = body_twist(T,  revolute)
//   T         = T @ srodrigues(revolute,  q[n,0])
//   priTwist  = body_twist(T,  prismatic)
//   T         = T @ srodrigues(prismatic, q[n,1])
// Memory-bound: ~144 MB fetch + 224 MB write per launch.

__device__ __forceinline__ void body_twist6(
    const float4& r0, const float4& r1, const float4& r2,
    float wx, float wy, float wz, float vx, float vy, float vz,
    float t[6])
{
    // p = T[:3,3]
    const float px = r0.w, py = r1.w, pz = r2.w;
    // u = v - cross(p, w)
    const float ux = vx - (py * wz - pz * wy);
    const float uy = vy - (pz * wx - px * wz);
    const float uz = vz - (px * wy - py * wx);
    // wb = R^T w  (column j of R dotted with w)
    t[0] = r0.x * wx + r1.x * wy + r2.x * wz;
    t[1] = r0.y * wx + r1.y * wy + r2.y * wz;
    t[2] = r0.z * wx + r1.z * wy + r2.z * wz;
    // vb = R^T u
    t[3] = r0.x * ux + r1.x * uy + r2.x * uz;
    t[4] = r0.y * ux + r1.y * uy + r2.y * uz;
    t[5] = r0.z * ux + r1.z * uy + r2.z * uz;
}

// T <- T @ srodrigues(xi, q), updating rows 0..2 in place. Row 3 stays [0,0,0,1].
__device__ __forceinline__ void apply_srodrigues(
    float4& r0, float4& r1, float4& r2,
    float th, bool rot,
    float wnx, float wny, float wnz,
    float vnx, float vny, float vnz,
    float vx, float vy, float vz,   // raw (unnormalized) v, for the !rot path
    float q)
{
    float R00, R01, R02, R10, R11, R12, R20, R21, R22, p0, p1, p2;
    if (rot) {
        const float phi = q * th;
        float s, cv;
        sincosf(phi, &s, &cv);
        const float c = 1.0f - cv;
        // R = I + s*skew(wn) + c*(wn wn^T - I)
        R00 = 1.0f + c * (wnx * wnx - 1.0f);
        R01 = -s * wnz + c * wnx * wny;
        R02 =  s * wny + c * wnx * wnz;
        R10 =  s * wnz + c * wny * wnx;
        R11 = 1.0f + c * (wny * wny - 1.0f);
        R12 = -s * wnx + c * wny * wnz;
        R20 = -s * wny + c * wnz * wnx;
        R21 =  s * wnx + c * wnz * wny;
        R22 = 1.0f + c * (wnz * wnz - 1.0f);
        // p = phi*vn + c*(wn x vn) + (phi - s)*(wn (wn.vn) - vn)
        const float d  = wnx * vnx + wny * vny + wnz * vnz;
        const float cx = wny * vnz - wnz * vny;
        const float cy = wnz * vnx - wnx * vnz;
        const float cz = wnx * vny - wny * vnx;
        const float ps = phi - s;
        p0 = phi * vnx + c * cx + ps * (wnx * d - vnx);
        p1 = phi * vny + c * cy + ps * (wny * d - vny);
        p2 = phi * vnz + c * cz + ps * (wnz * d - vnz);
    } else {
        R00 = 1.0f; R01 = 0.0f; R02 = 0.0f;
        R10 = 0.0f; R11 = 1.0f; R12 = 0.0f;
        R20 = 0.0f; R21 = 0.0f; R22 = 1.0f;
        p0 = q * vx; p1 = q * vy; p2 = q * vz;
    }
    // T = T @ [[R, p],[0,0,0,1]]  (rows 0..2)
    float4 n0, n1, n2;
    n0.x = r0.x * R00 + r0.y * R10 + r0.z * R20;
    n0.y = r0.x * R01 + r0.y * R11 + r0.z * R21;
    n0.z = r0.x * R02 + r0.y * R12 + r0.z * R22;
    n0.w = r0.x * p0  + r0.y * p1  + r0.z * p2 + r0.w;
    n1.x = r1.x * R00 + r1.y * R10 + r1.z * R20;
    n1.y = r1.x * R01 + r1.y * R11 + r1.z * R21;
    n1.z = r1.x * R02 + r1.y * R12 + r1.z * R22;
    n1.w = r1.x * p0  + r1.y * p1  + r1.z * p2 + r1.w;
    n2.x = r2.x * R00 + r2.y * R10 + r2.z * R20;
    n2.y = r2.x * R01 + r2.y * R11 + r2.z * R21;
    n2.z = r2.x * R02 + r2.y * R12 + r2.z * R22;
    n2.w = r2.x * p0  + r2.y * p1  + r2.z * p2 + r2.w;
    r0 = n0; r1 = n1; r2 = n2;
}

__global__ __launch_bounds__(256) void twist_66322884985439_kernel(
    const float* __restrict__ Tin,   // n*16, row-major 4x4
    const float* __restrict__ q2,    // n*2
    const float* __restrict__ rev,   // 6
    const float* __restrict__ pri,   // 6
    float* __restrict__ outRev,      // n*6
    float* __restrict__ outPri,      // n*6
    float* __restrict__ outT,        // n*16
    int n)
{
    const int i = blockIdx.x * blockDim.x + threadIdx.x;
    if (i >= n) return;

    // Uniform twist constants (broadcast loads).
    const float rwx = rev[0], rwy = rev[1], rwz = rev[2];
    const float rvx = rev[3], rvy = rev[4], rvz = rev[5];
    const float pwx = pri[0], pwy = pri[1], pwz = pri[2];
    const float pvx = pri[3], pvy = pri[4], pvz = pri[5];

    // Normalized forms (uniform, cheap).
    const float rth  = sqrtf(rwx * rwx + rwy * rwy + rwz * rwz);
    const float rinv = 1.0f / fmaxf(rth, 1e-12f);
    const bool  rrot = rth > 1e-9f;
    const float rwnx = rwx * rinv, rwny = rwy * rinv, rwnz = rwz * rinv;
    const float rvnx = rvx * rinv, rvny = rvy * rinv, rvnz = rvz * rinv;

    const float pth  = sqrtf(pwx * pwx + pwy * pwy + pwz * pwz);
    const float pinv = 1.0f / fmaxf(pth, 1e-12f);
    const bool  prot = pth > 1e-9f;
    const float pwnx = pwx * pinv, pwny = pwy * pinv, pwnz = pwz * pinv;
    const float pvnx = pvx * pinv, pvny = pvy * pinv, pvnz = pvz * pinv;

    // Load T rows 0..2 (row 3 is [0,0,0,1] and never changes).
    const float4* Tp = reinterpret_cast<const float4*>(Tin + (size_t)i * 16);
    float4 r0 = Tp[0];
    float4 r1 = Tp[1];
    float4 r2 = Tp[2];

    const float2 q = *reinterpret_cast<const float2*>(q2 + (size_t)i * 2);

    // 1) revolute twist from original T
    float tr[6];
    body_twist6(r0, r1, r2, rwx, rwy, rwz, rvx, rvy, rvz, tr);

    // 2) T = T @ srodrigues(revolute, q0)
    apply_srodrigues(r0, r1, r2, rth, rrot, rwnx, rwny, rwnz, rvnx, rvny, rvnz,
                     rvx, rvy, rvz, q.x);

    // 3) prismatic twist from updated T
    float tp[6];
    body_twist6(r0, r1, r2, pwx, pwy, pwz, pvx, pvy, pvz, tp);

    // 4) T = T @ srodrigues(prismatic, q1)
    apply_srodrigues(r0, r1, r2, pth, prot, pwnx, pwny, pwnz, pvnx, pvny, pvnz,
                     pvx, pvy, pvz, q.y);

    // Stores: 3x float2 per twist (8B aligned: i*24 bytes), 4x float4 for T.
    float2* orv = reinterpret_cast<float2*>(outRev + (size_t)i * 6);
    orv[0] = make_float2(tr[0], tr[1]);
    orv[1] = make_float2(tr[2], tr[3]);
    orv[2] = make_float2(tr[4], tr[5]);

    float2* opv = reinterpret_cast<float2*>(outPri + (size_t)i * 6);
    opv[0] = make_float2(tp[0], tp[1]);
    opv[1] = make_float2(tp[2], tp[3]);
    opv[2] = make_float2(tp[4], tp[5]);

    float4* ot = reinterpret_cast<float4*>(outT + (size_t)i * 16);
    ot[0] = r0;
    ot[1] = r1;
    ot[2] = r2;
    ot[3] = make_float4(0.0f, 0.0f, 0.0f, 1.0f);
}

extern "C" void kernel_launch(void* const* d_in, const int* in_sizes, int n_in,
                              void* d_out, int out_size, void* d_ws, size_t ws_size,
                              hipStream_t stream) {
    const float* Tin = (const float*)d_in[0];   // (N,4,4) fp32
    const float* q2  = (const float*)d_in[1];   // (N,2)   fp32
    const float* rev = (const float*)d_in[2];   // (6,)    fp32
    const float* pri = (const float*)d_in[3];   // (6,)    fp32

    const int n = in_sizes[0] / 16;

    float* out = (float*)d_out;
    float* outRev = out;                        // n*6
    float* outPri = out + (size_t)n * 6;        // n*6
    float* outT   = out + (size_t)n * 12;       // n*16

    const int block = 256;
    const int grid = (n + block - 1) / block;
    twist_66322884985439_kernel<<<grid, block, 0, stream>>>(
        Tin, q2, rev, pri, outRev, outPri, outT, n);
}